// Round 1
// baseline (416.677 us; speedup 1.0000x reference)
//
#include <hip/hip_runtime.h>
#include <hip/hip_bf16.h>

#define NUM_CLASS 21
#define IGNORE_L 255
#define EPSF 1e-6f
// Problem dims (fixed by setup_inputs): B=8, D=512, H=W=128 -> HW=16384
#define BATCH 8
#define DCH 512
#define HW 16384

__device__ __forceinline__ float waveReduce(float v) {
    #pragma unroll
    for (int m = 1; m < 64; m <<= 1) v += __shfl_xor(v, m, 64);
    return v;
}

// ---------------------------------------------------------------------------
// Kernel 1: per-(b,d) row segmented class sums + global sum of squares.
// One block per row (b*512+d). LDS slots [class][lane] -> bank = lane%32,
// conflict-free; ds_add_f32 atomics (no RMW chain). Each class_sum[b][c][d]
// written by exactly one block -> plain store (deterministic).
// ---------------------------------------------------------------------------
__global__ __launch_bounds__(256) void car_scatter_kernel(
    const float* __restrict__ features, const int* __restrict__ label,
    float* __restrict__ class_sum, float* __restrict__ sumsq)
{
    __shared__ float sm[NUM_CLASS * 64];
    __shared__ float red[4];
    const int t = threadIdx.x;
    const int lane = t & 63;
    const int wave = t >> 6;
    const int row = blockIdx.x;      // b*512 + d
    const int b = row >> 9;
    const int d = row & 511;

    for (int i = t; i < NUM_CLASS * 64; i += 256) sm[i] = 0.0f;
    __syncthreads();

    const float4* __restrict__ frow = (const float4*)(features + (size_t)row * HW);
    const int4*  __restrict__ lrow = (const int4*)(label + (size_t)b * HW);

    float ss = 0.0f;
    #pragma unroll 4
    for (int i = 0; i < HW / (256 * 4); ++i) {
        float4 f = frow[i * 256 + t];
        int4   l = lrow[i * 256 + t];
        if (l.x != IGNORE_L) ss += f.x * f.x;
        if ((unsigned)l.x < NUM_CLASS) atomicAdd(&sm[l.x * 64 + lane], f.x);
        if (l.y != IGNORE_L) ss += f.y * f.y;
        if ((unsigned)l.y < NUM_CLASS) atomicAdd(&sm[l.y * 64 + lane], f.y);
        if (l.z != IGNORE_L) ss += f.z * f.z;
        if ((unsigned)l.z < NUM_CLASS) atomicAdd(&sm[l.z * 64 + lane], f.z);
        if (l.w != IGNORE_L) ss += f.w * f.w;
        if ((unsigned)l.w < NUM_CLASS) atomicAdd(&sm[l.w * 64 + lane], f.w);
    }
    __syncthreads();

    // Reduce each class's 64 lane-slots via shuffle; wave w handles c=w,w+4,...
    float* __restrict__ out_row = class_sum + (size_t)b * NUM_CLASS * DCH + d;
    for (int c = wave; c < NUM_CLASS; c += 4) {
        float v = sm[c * 64 + lane];
        v = waveReduce(v);
        if (lane == 0) out_row[(size_t)c * DCH] = v;
    }

    ss = waveReduce(ss);
    if (lane == 0) red[wave] = ss;
    __syncthreads();
    if (t == 0) atomicAdd(sumsq, red[0] + red[1] + red[2] + red[3]);
}

// ---------------------------------------------------------------------------
// Kernel 2: per-batch class histogram (counts) + total valid count.
// ---------------------------------------------------------------------------
__global__ __launch_bounds__(256) void car_counts_kernel(
    const int* __restrict__ label, float* __restrict__ counts,
    float* __restrict__ total)
{
    __shared__ float sm[NUM_CLASS * 64];
    __shared__ float red[4];
    const int t = threadIdx.x;
    const int lane = t & 63;
    const int wave = t >> 6;
    const int b = blockIdx.x;

    for (int i = t; i < NUM_CLASS * 64; i += 256) sm[i] = 0.0f;
    __syncthreads();

    const int4* __restrict__ lrow = (const int4*)(label + (size_t)b * HW);
    float tv = 0.0f;
    #pragma unroll 4
    for (int i = 0; i < HW / (256 * 4); ++i) {
        int4 l = lrow[i * 256 + t];
        if (l.x != IGNORE_L) tv += 1.0f;
        if ((unsigned)l.x < NUM_CLASS) atomicAdd(&sm[l.x * 64 + lane], 1.0f);
        if (l.y != IGNORE_L) tv += 1.0f;
        if ((unsigned)l.y < NUM_CLASS) atomicAdd(&sm[l.y * 64 + lane], 1.0f);
        if (l.z != IGNORE_L) tv += 1.0f;
        if ((unsigned)l.z < NUM_CLASS) atomicAdd(&sm[l.z * 64 + lane], 1.0f);
        if (l.w != IGNORE_L) tv += 1.0f;
        if ((unsigned)l.w < NUM_CLASS) atomicAdd(&sm[l.w * 64 + lane], 1.0f);
    }
    __syncthreads();

    for (int c = wave; c < NUM_CLASS; c += 4) {
        float v = sm[c * 64 + lane];
        v = waveReduce(v);
        if (lane == 0) counts[b * NUM_CLASS + c] = v;
    }

    tv = waveReduce(tv);
    if (lane == 0) red[wave] = tv;
    __syncthreads();
    if (t == 0) atomicAdd(total, red[0] + red[1] + red[2] + red[3]);
}

// ---------------------------------------------------------------------------
// Kernel 3: finalize (1 block, 512 threads).
//  A: centers, intra correction  corr = sum cen*(n*cen - 2S); batch-mean cm.
//  C: per-class norms of cm.   D: 21x21 cosine sim -> inter loss.
//  out[0] = (sumsq + corr)/(total+eps); out[1] = sum relu(sim-.5)/(21+eps).
// ---------------------------------------------------------------------------
__global__ __launch_bounds__(512) void car_finalize_kernel(
    const float* __restrict__ class_sum, const float* __restrict__ counts,
    const float* __restrict__ scalars /* [0]=sumsq [1]=total */,
    float* __restrict__ out)
{
    __shared__ float cm[NUM_CLASS * DCH];
    __shared__ float norms[NUM_CLASS];
    __shared__ float redA[8];
    __shared__ float redB[8];
    const int t = threadIdx.x;
    const int lane = t & 63;
    const int wave = t >> 6;

    // Phase A: thread owns (c,d) pairs p = c*512 + d, loops over batches.
    float corr = 0.0f;
    for (int p = t; p < NUM_CLASS * DCH; p += 512) {
        const int c = p >> 9;  // p / 512
        float s = 0.0f;
        #pragma unroll
        for (int b = 0; b < BATCH; ++b) {
            float S = class_sum[(size_t)b * NUM_CLASS * DCH + p];
            float n = counts[b * NUM_CLASS + c];
            float cen = S / (n + EPSF);
            corr += cen * (n * cen - 2.0f * S);
            s += cen;
        }
        cm[p] = s * (1.0f / BATCH);
    }
    corr = waveReduce(corr);
    if (lane == 0) redA[wave] = corr;
    __syncthreads();   // also publishes cm[]

    // Phase C: per-class L2 norm of cm. Wave w handles c = w, w+8, ...
    for (int c = wave; c < NUM_CLASS; c += 8) {
        float s = 0.0f;
        #pragma unroll
        for (int k = 0; k < DCH / 64; ++k) {
            float v = cm[c * DCH + k * 64 + lane];
            s += v * v;
        }
        s = waveReduce(s);
        if (lane == 0) norms[c] = fmaxf(sqrtf(s), 1e-12f);
    }
    __syncthreads();

    // Phase D: all off-diagonal pairs.
    float interAcc = 0.0f;
    for (int p = wave; p < NUM_CLASS * NUM_CLASS; p += 8) {
        const int c1 = p / NUM_CLASS;
        const int c2 = p % NUM_CLASS;
        if (c1 == c2) continue;
        float s = 0.0f;
        #pragma unroll
        for (int k = 0; k < DCH / 64; ++k)
            s += cm[c1 * DCH + k * 64 + lane] * cm[c2 * DCH + k * 64 + lane];
        s = waveReduce(s);
        if (lane == 0) {
            float sim = s / (norms[c1] * norms[c2]);
            interAcc += fmaxf(sim - 0.5f, 0.0f);
        }
    }
    if (lane == 0) redB[wave] = interAcc;
    __syncthreads();

    if (t == 0) {
        float corrT = 0.0f, interT = 0.0f;
        #pragma unroll
        for (int w = 0; w < 8; ++w) { corrT += redA[w]; interT += redB[w]; }
        const float ss  = scalars[0];
        const float tot = scalars[1];
        out[0] = (ss + corrT) / (tot + EPSF);                 // intra * 1.0
        out[1] = interT / ((float)NUM_CLASS + EPSF);          // inter * 1.0
    }
}

extern "C" void kernel_launch(void* const* d_in, const int* in_sizes, int n_in,
                              void* d_out, int out_size, void* d_ws, size_t ws_size,
                              hipStream_t stream) {
    const float* features = (const float*)d_in[0];
    const int*   label    = (const int*)d_in[1];
    float* out = (float*)d_out;

    // ws layout (floats): [0]=sumsq, [1]=total, [2..170)=counts(8*21),
    // [256..256+86016)=class_sum[8][21][512]
    float* ws        = (float*)d_ws;
    float* sumsq     = ws + 0;
    float* total     = ws + 1;
    float* counts    = ws + 2;
    float* class_sum = ws + 256;

    hipMemsetAsync(ws, 0, 2 * sizeof(float), stream);  // zero the two atomics

    car_counts_kernel<<<BATCH, 256, 0, stream>>>(label, counts, total);
    car_scatter_kernel<<<BATCH * DCH, 256, 0, stream>>>(features, label, class_sum, sumsq);
    car_finalize_kernel<<<1, 512, 0, stream>>>(class_sum, counts, ws, out);
}

// Round 2
// 408.822 us; speedup vs baseline: 1.0192x; 1.0192x over previous
//
#include <hip/hip_runtime.h>
#include <hip/hip_bf16.h>

#define NUM_CLASS 21
#define IGNORE_L 255
#define EPSF 1e-6f
// Problem dims (fixed by setup_inputs): B=8, D=512, H=W=128 -> HW=16384
#define BATCH 8
#define DCH 512
#define HW 16384
#define NROWS (BATCH * DCH)   // 4096 scatter blocks

__device__ __forceinline__ float waveReduce(float v) {
    #pragma unroll
    for (int m = 1; m < 64; m <<= 1) v += __shfl_xor(v, m, 64);
    return v;
}

// ---------------------------------------------------------------------------
// Kernel 1: per-(b,d) row segmented class sums + per-block sum of squares.
// One block per row (b*512+d). LDS slots [class][lane] -> bank = lane%32,
// 2-way aliasing (free); native ds_add_f32 atomics. Each class_sum[b][c][d]
// and ss_parts[row] written by exactly one block -> plain stores, no global
// atomics (global f32 atomicAdd = CAS loop = serialization).
// ---------------------------------------------------------------------------
__global__ __launch_bounds__(256) void car_scatter_kernel(
    const float* __restrict__ features, const int* __restrict__ label,
    float* __restrict__ class_sum, float* __restrict__ ss_parts)
{
    __shared__ float sm[NUM_CLASS * 64];
    __shared__ float red[4];
    const int t = threadIdx.x;
    const int lane = t & 63;
    const int wave = t >> 6;
    const int row = blockIdx.x;      // b*512 + d
    const int b = row >> 9;
    const int d = row & 511;

    for (int i = t; i < NUM_CLASS * 64; i += 256) sm[i] = 0.0f;
    __syncthreads();

    const float4* __restrict__ frow = (const float4*)(features + (size_t)row * HW);
    const int4*  __restrict__ lrow = (const int4*)(label + (size_t)b * HW);

    float ss = 0.0f;
    #pragma unroll 4
    for (int i = 0; i < HW / (256 * 4); ++i) {
        float4 f = frow[i * 256 + t];
        int4   l = lrow[i * 256 + t];
        if (l.x != IGNORE_L) ss += f.x * f.x;
        if ((unsigned)l.x < NUM_CLASS) atomicAdd(&sm[l.x * 64 + lane], f.x);
        if (l.y != IGNORE_L) ss += f.y * f.y;
        if ((unsigned)l.y < NUM_CLASS) atomicAdd(&sm[l.y * 64 + lane], f.y);
        if (l.z != IGNORE_L) ss += f.z * f.z;
        if ((unsigned)l.z < NUM_CLASS) atomicAdd(&sm[l.z * 64 + lane], f.z);
        if (l.w != IGNORE_L) ss += f.w * f.w;
        if ((unsigned)l.w < NUM_CLASS) atomicAdd(&sm[l.w * 64 + lane], f.w);
    }
    __syncthreads();

    // Reduce each class's 64 lane-slots via shuffle; wave w handles c=w,w+4,...
    float* __restrict__ out_row = class_sum + (size_t)b * NUM_CLASS * DCH + d;
    for (int c = wave; c < NUM_CLASS; c += 4) {
        float v = sm[c * 64 + lane];
        v = waveReduce(v);
        if (lane == 0) out_row[(size_t)c * DCH] = v;
    }

    ss = waveReduce(ss);
    if (lane == 0) red[wave] = ss;
    __syncthreads();
    if (t == 0) ss_parts[row] = red[0] + red[1] + red[2] + red[3];
}

// ---------------------------------------------------------------------------
// Kernel 2: per-batch class histogram (counts) + per-batch valid count.
// ---------------------------------------------------------------------------
__global__ __launch_bounds__(256) void car_counts_kernel(
    const int* __restrict__ label, float* __restrict__ counts,
    float* __restrict__ total_parts)
{
    __shared__ float sm[NUM_CLASS * 64];
    __shared__ float red[4];
    const int t = threadIdx.x;
    const int lane = t & 63;
    const int wave = t >> 6;
    const int b = blockIdx.x;

    for (int i = t; i < NUM_CLASS * 64; i += 256) sm[i] = 0.0f;
    __syncthreads();

    const int4* __restrict__ lrow = (const int4*)(label + (size_t)b * HW);
    float tv = 0.0f;
    #pragma unroll 4
    for (int i = 0; i < HW / (256 * 4); ++i) {
        int4 l = lrow[i * 256 + t];
        if (l.x != IGNORE_L) tv += 1.0f;
        if ((unsigned)l.x < NUM_CLASS) atomicAdd(&sm[l.x * 64 + lane], 1.0f);
        if (l.y != IGNORE_L) tv += 1.0f;
        if ((unsigned)l.y < NUM_CLASS) atomicAdd(&sm[l.y * 64 + lane], 1.0f);
        if (l.z != IGNORE_L) tv += 1.0f;
        if ((unsigned)l.z < NUM_CLASS) atomicAdd(&sm[l.z * 64 + lane], 1.0f);
        if (l.w != IGNORE_L) tv += 1.0f;
        if ((unsigned)l.w < NUM_CLASS) atomicAdd(&sm[l.w * 64 + lane], 1.0f);
    }
    __syncthreads();

    for (int c = wave; c < NUM_CLASS; c += 4) {
        float v = sm[c * 64 + lane];
        v = waveReduce(v);
        if (lane == 0) counts[b * NUM_CLASS + c] = v;
    }

    tv = waveReduce(tv);
    if (lane == 0) red[wave] = tv;
    __syncthreads();
    if (t == 0) total_parts[b] = red[0] + red[1] + red[2] + red[3];
}

// ---------------------------------------------------------------------------
// Kernel 3: finalize (1 block, 512 threads).
//  0: sum ss_parts[4096].
//  A: centers, intra correction  corr = sum cen*(n*cen - 2S); batch-mean cm.
//  C: per-class norms of cm.   D: 21x21 cosine sim -> inter loss.
//  out[0] = (ss + corr)/(total+eps); out[1] = sum relu(sim-.5)/(21+eps).
// ---------------------------------------------------------------------------
__global__ __launch_bounds__(512) void car_finalize_kernel(
    const float* __restrict__ class_sum, const float* __restrict__ counts,
    const float* __restrict__ ss_parts, const float* __restrict__ total_parts,
    float* __restrict__ out)
{
    __shared__ float cm[NUM_CLASS * DCH];
    __shared__ float norms[NUM_CLASS];
    __shared__ float redC[8];   // corr partials
    __shared__ float redS[8];   // sumsq partials
    __shared__ float redB[8];   // inter partials
    const int t = threadIdx.x;
    const int lane = t & 63;
    const int wave = t >> 6;

    // Phase 0: sum of per-block sum-of-squares partials.
    float ssp = 0.0f;
    #pragma unroll
    for (int i = 0; i < NROWS / 512; ++i) ssp += ss_parts[i * 512 + t];

    // Phase A: thread owns (c,d) pairs p = c*512 + d, loops over batches.
    float corr = 0.0f;
    for (int p = t; p < NUM_CLASS * DCH; p += 512) {
        const int c = p >> 9;  // p / 512
        float s = 0.0f;
        #pragma unroll
        for (int b = 0; b < BATCH; ++b) {
            float S = class_sum[(size_t)b * NUM_CLASS * DCH + p];
            float n = counts[b * NUM_CLASS + c];
            float cen = S / (n + EPSF);
            corr += cen * (n * cen - 2.0f * S);
            s += cen;
        }
        cm[p] = s * (1.0f / BATCH);
    }
    corr = waveReduce(corr);
    ssp  = waveReduce(ssp);
    if (lane == 0) { redC[wave] = corr; redS[wave] = ssp; }
    __syncthreads();   // also publishes cm[]

    // Phase C: per-class L2 norm of cm. Wave w handles c = w, w+8, ...
    for (int c = wave; c < NUM_CLASS; c += 8) {
        float s = 0.0f;
        #pragma unroll
        for (int k = 0; k < DCH / 64; ++k) {
            float v = cm[c * DCH + k * 64 + lane];
            s += v * v;
        }
        s = waveReduce(s);
        if (lane == 0) norms[c] = fmaxf(sqrtf(s), 1e-12f);
    }
    __syncthreads();

    // Phase D: all off-diagonal pairs.
    float interAcc = 0.0f;
    for (int p = wave; p < NUM_CLASS * NUM_CLASS; p += 8) {
        const int c1 = p / NUM_CLASS;
        const int c2 = p % NUM_CLASS;
        if (c1 == c2) continue;
        float s = 0.0f;
        #pragma unroll
        for (int k = 0; k < DCH / 64; ++k)
            s += cm[c1 * DCH + k * 64 + lane] * cm[c2 * DCH + k * 64 + lane];
        s = waveReduce(s);
        if (lane == 0) {
            float sim = s / (norms[c1] * norms[c2]);
            interAcc += fmaxf(sim - 0.5f, 0.0f);
        }
    }
    if (lane == 0) redB[wave] = interAcc;
    __syncthreads();

    if (t == 0) {
        float corrT = 0.0f, interT = 0.0f, ssT = 0.0f, tot = 0.0f;
        #pragma unroll
        for (int w = 0; w < 8; ++w) { corrT += redC[w]; interT += redB[w]; ssT += redS[w]; }
        #pragma unroll
        for (int b = 0; b < BATCH; ++b) tot += total_parts[b];
        out[0] = (ssT + corrT) / (tot + EPSF);                // intra * 1.0
        out[1] = interT / ((float)NUM_CLASS + EPSF);          // inter * 1.0
    }
}

extern "C" void kernel_launch(void* const* d_in, const int* in_sizes, int n_in,
                              void* d_out, int out_size, void* d_ws, size_t ws_size,
                              hipStream_t stream) {
    const float* features = (const float*)d_in[0];
    const int*   label    = (const int*)d_in[1];
    float* out = (float*)d_out;

    // ws layout (floats):
    //   [0 .. 4096)          ss_parts (one per scatter block)
    //   [4096 .. 4104)       total_parts (one per batch)
    //   [4104 .. 4272)       counts (8*21)
    //   [4352 .. 4352+86016) class_sum[8][21][512]
    float* ws          = (float*)d_ws;
    float* ss_parts    = ws + 0;
    float* total_parts = ws + 4096;
    float* counts      = ws + 4104;
    float* class_sum   = ws + 4352;

    car_counts_kernel<<<BATCH, 256, 0, stream>>>(label, counts, total_parts);
    car_scatter_kernel<<<NROWS, 256, 0, stream>>>(features, label, class_sum, ss_parts);
    car_finalize_kernel<<<1, 512, 0, stream>>>(class_sum, counts, ss_parts, total_parts, out);
}